// Round 13
// baseline (132.220 us; speedup 1.0000x reference)
//
#include <hip/hip_runtime.h>
#include <hip/hip_bf16.h>
#include <stdint.h>

// B=8, n=64, C=32, O=32
#define NC   2048      // n*C
#define NNC  131072    // n*n*C
#define N3C  8388608   // n*n*n*C per batch
#define CMPE 1048576   // per-comp elements (B*n*n*C)
#define ASP  392       // k_out LDS row pitch in u16 (16B-aligned: 784B)
#define S3R  1168      // s3l jj-stride in u16 (32*36 + 16 pad -> 8-bank skew)

typedef unsigned short u16;
typedef short bf16x8 __attribute__((ext_vector_type(8)));
typedef float f32x4  __attribute__((ext_vector_type(4)));

__device__ __forceinline__ u16 bf16b(float x){
    unsigned u = __float_as_uint(x);
    u += 0x7FFFu + ((u >> 16) & 1u);      // RNE
    return (u16)(u >> 16);
}
__device__ __forceinline__ float b2f(u16 h){ return __uint_as_float(((unsigned)h) << 16); }
__device__ __forceinline__ float lo16(unsigned u){ return __uint_as_float(u << 16); }
__device__ __forceinline__ float hi16(unsigned u){ return __uint_as_float(u & 0xFFFF0000u); }
__device__ __forceinline__ void f4acc(float4& a, const float4 b){
    a.x += b.x; a.y += b.y; a.z += b.z; a.w += b.w;
}
__device__ __forceinline__ void addp4(float4& a, const uint2 u){
    a.x += lo16(u.x); a.y += hi16(u.x); a.z += lo16(u.y); a.w += hi16(u.y);
}
__device__ __forceinline__ uint2 pack4(float4 v){
    uint2 r;
    r.x = (unsigned)bf16b(v.x) | ((unsigned)bf16b(v.y) << 16);
    r.y = (unsigned)bf16b(v.z) | ((unsigned)bf16b(v.w) << 16);
    return r;
}
__device__ __forceinline__ uint2 pack4s(float4 v, float s){
    v.x *= s; v.y *= s; v.z *= s; v.w *= s;
    return pack4(v);
}
__device__ __forceinline__ uint2 pack4t(float4 v){   // truncating bf16 pack
    uint2 r;
    r.x = (__float_as_uint(v.x) >> 16) | (__float_as_uint(v.y) & 0xFFFF0000u);
    r.y = (__float_as_uint(v.z) >> 16) | (__float_as_uint(v.w) & 0xFFFF0000u);
    return r;
}

// ---------------------------------------------------------------------------
// K1: Block=(b, ig, jg, kh). 256 threads=(ktl,c4). 1024 blocks = 4/CU.
// Double-buffered s3l [jj][ktl][c] with ONE ds_write_b64 per (ii,jj)
// (truncating bf16 pack). One barrier per ii. vn-prefetch. First 41 blocks
// zero the a1/a0 atomic-target region.
__global__ __launch_bounds__(256, 4) void k_pass1(
    const float* __restrict__ x,
    u16* __restrict__ p1, u16* __restrict__ p2,
    u16* __restrict__ s3ph, u16* __restrict__ c_d12,
    u16* __restrict__ c_d13, u16* __restrict__ c_d23,
    float* __restrict__ a1z)
{
    int blk = blockIdx.x;                 // ((b*8+ig)*8+jg)*2+kh
    int kh = blk & 1, jg = (blk >> 1) & 7, ig = (blk >> 4) & 7, b = blk >> 7;
    int t = threadIdx.x;                  // 0..255
    int ktl = t >> 3, kt = kh * 32 + ktl, c4 = (t & 7) * 4;

    if (blk < 41){                        // zero a1+a0 (165120 f; overshoot
        float4 z = make_float4(0,0,0,0);  //  lands in u1p, overwritten later)
        *reinterpret_cast<float4*>(a1z + (size_t)blk * 4096 + 4 * t)        = z;
        *reinterpret_cast<float4*>(a1z + (size_t)blk * 4096 + 1024 + 4 * t) = z;
        *reinterpret_cast<float4*>(a1z + (size_t)blk * 4096 + 2048 + 4 * t) = z;
        *reinterpret_cast<float4*>(a1z + (size_t)blk * 4096 + 3072 + 4 * t) = z;
    }

    __shared__ u16 s3l[2][8 * S3R];       // [parity][jj*S3R + ktl*36 + c] ~37.4KB

    float4 p1a[8];
    #pragma unroll
    for (int a = 0; a < 8; ++a) p1a[a] = make_float4(0,0,0,0);

    const float* xb = x + (size_t)b * N3C + (size_t)ig * 8 * NNC
                        + (size_t)jg * 8 * NC + (size_t)kh * 1024;

    int rjj = t >> 4, rcp = t & 15;       // reduce mapping (128 threads: 8 x 16)
    int par = 0;
    int wslot = ktl * 36 + c4;            // s3l write offset within jj row

    float4 v[8];
    #pragma unroll
    for (int jj = 0; jj < 8; ++jj)
        v[jj] = *reinterpret_cast<const float4*>(xb + (size_t)jj * NC + 4 * t);

    for (int ii = 0; ii < 8; ++ii){
        int i = ig * 8 + ii;
        float4 q = make_float4(0,0,0,0);
        #pragma unroll
        for (int jj = 0; jj < 8; ++jj){
            int j = jg * 8 + jj;
            f4acc(p1a[jj], v[jj]);
            f4acc(q, v[jj]);
            *reinterpret_cast<uint2*>(&s3l[par][jj * S3R + wslot]) = pack4t(v[jj]);
            if (kt == i)    // d13[b,i,j,c] = x[b,i,j,i,c]
                *reinterpret_cast<uint2*>(c_d13 + (((size_t)(b * 64 + i)) * 64 + j) * 32 + c4) = pack4(v[jj]);
            if (kt == j)    // d23[b,i,j,c] = x[b,i,j,j,c]
                *reinterpret_cast<uint2*>(c_d23 + (((size_t)(b * 64 + i)) * 64 + j) * 32 + c4) = pack4(v[jj]);
            if (i == j)     // d12[b,i,k,c] = x[b,i,i,k,c]; elem = kh*1024+4t
                *reinterpret_cast<uint2*>(c_d12 + ((size_t)(b * 64 + i)) * 2048 + kh * 1024 + 4 * (size_t)t) = pack4(v[jj]);
        }
        // p2 partial row (sum over this jg's 8 j), this k-half
        *reinterpret_cast<uint2*>(p2 + ((size_t)((b * 8 + jg) * 64 + i)) * 2048 + kh * 1024 + 4 * (size_t)t) = pack4(q);

        __syncthreads();                  // publish s3l[par] writes
        // prefetch next ii while the LDS reduce runs
        float4 vn[8];
        if (ii < 7){
            #pragma unroll
            for (int jj = 0; jj < 8; ++jj)
                vn[jj] = *reinterpret_cast<const float4*>(xb + (size_t)(ii + 1) * NNC + (size_t)jj * NC + 4 * t);
        }
        if (t < 128){   // s3 half-partial reduce over ktl (32 b32 reads, 2 c's)
            const u16* sp = &s3l[par][rjj * S3R + rcp * 2];
            float s0 = 0.f, s1v = 0.f;
            #pragma unroll
            for (int g = 0; g < 32; ++g){
                unsigned u = *reinterpret_cast<const unsigned*>(sp + g * 36);
                s0  += lo16(u);
                s1v += hi16(u);
            }
            unsigned outp = (unsigned)bf16b(s0) | ((unsigned)bf16b(s1v) << 16);
            *reinterpret_cast<unsigned*>(s3ph + (size_t)kh * 1048576
                + (((size_t)(b * 64 + i)) * 64 + jg * 8 + rjj) * 32 + rcp * 2) = outp;
        }
        par ^= 1;                         // next ii writes the other buffer
        if (ii < 7){
            #pragma unroll
            for (int jj = 0; jj < 8; ++jj) v[jj] = vn[jj];
        }
    }
    #pragma unroll
    for (int jj = 0; jj < 8; ++jj)
        *reinterpret_cast<uint2*>(p1 + ((size_t)((b * 8 + ig) * 64 + jg * 8 + jj)) * 2048 + kh * 1024 + 4 * (size_t)t) = pack4(p1a[jj]);
}

// ---------------------------------------------------------------------------
// K2: reduce partials -> s1/s2 comps and combine s3 halves (bf16 means).
__global__ __launch_bounds__(256) void k_reduce(
    const u16* __restrict__ p1, const u16* __restrict__ p2,
    const u16* __restrict__ s3ph,
    u16* __restrict__ c_s1, u16* __restrict__ c_s2, u16* __restrict__ c_s3)
{
    int blk = blockIdx.x;
    int b = blk / 96, rr = blk % 96, sx = rr >> 5, ch = rr & 31;
    int t = threadIdx.x;
    if (sx == 2){
        #pragma unroll
        for (int r2 = 0; r2 < 2; ++r2){
            int row = ch * 2 + r2;
            #pragma unroll
            for (int e = 0; e < 2; ++e){
                size_t base = ((size_t)(b * 64 + row)) * 2048 + e * 1024 + 4 * t;
                float4 a = make_float4(0,0,0,0);
                addp4(a, *reinterpret_cast<const uint2*>(s3ph + base));
                addp4(a, *reinterpret_cast<const uint2*>(s3ph + 1048576 + base));
                *reinterpret_cast<uint2*>(c_s3 + base) = pack4s(a, 1.f/64.f);
            }
        }
        return;
    }
    const u16* P = sx ? p2 : p1;
    u16* O = sx ? c_s2 : c_s1;
    #pragma unroll
    for (int r2 = 0; r2 < 2; ++r2){
        int row = ch * 2 + r2;
        float4 a0v = make_float4(0,0,0,0), a1v = make_float4(0,0,0,0);
        #pragma unroll
        for (int g = 0; g < 8; ++g){
            const u16* src = P + ((size_t)((b * 8 + g) * 64 + row)) * 2048;
            addp4(a0v, *reinterpret_cast<const uint2*>(src + 4 * t));
            addp4(a1v, *reinterpret_cast<const uint2*>(src + 1024 + 4 * t));
        }
        u16* ob = O + ((size_t)(b * 64 + row)) * 2048;
        *reinterpret_cast<uint2*>(ob + 4 * t)        = pack4s(a0v, 1.f/64.f);
        *reinterpret_cast<uint2*>(ob + 1024 + 4 * t) = pack4s(a1v, 1.f/64.f);
    }
}

// ---------------------------------------------------------------------------
// K3: a1 [B][64][320], a0 [B][160] from bf16 comps. 160 blocks:
// (b*5+m)*4 + pc. Row-chunks direct-write; col/a0/diag via atomicAdd
// (region pre-zeroed by k_pass1).
__global__ __launch_bounds__(256) void k_a1a0(
    const u16* __restrict__ comps,
    float* __restrict__ a1, float* __restrict__ a0)
{
    int blk = blockIdx.x;                 // 160: (b*5+m)*4 + pc
    int pc = blk & 3, m = (blk >> 2) % 5, b = blk / 20;
    const int cidx [5] = {0, 1, 3, 4, 5};
    const int rowch[5] = {1, 2, 4, 6, 8};
    const int colch[5] = {0, -1, 3, 5, 7};
    const int a0i  [5] = {0, -1, 1, 2, 3};

    const u16* M = comps + (size_t)cidx[m] * CMPE + (size_t)b * NNC;
    int t = threadIdx.x, c = t & 31, qb = (t >> 5) * 8;
    int p0 = pc * 16;
    float colacc[8] = {0,0,0,0,0,0,0,0};
    __shared__ float red[2048];
    __shared__ float rowc[16][32];
    for (int pp0 = 0; pp0 < 16; pp0 += 8){
        #pragma unroll
        for (int pp = 0; pp < 8; ++pp){
            const u16* row = M + (size_t)(p0 + pp0 + pp) * 2048;
            float part = 0.f;
            #pragma unroll
            for (int kk = 0; kk < 8; ++kk){
                float v = b2f(row[(qb + kk) * 32 + c]);
                colacc[kk] += v; part += v;
            }
            red[pp * 256 + t] = part;
        }
        __syncthreads();
        {
            int pp = t >> 5, cc = t & 31;
            float ssum = 0.f;
            #pragma unroll
            for (int g = 0; g < 8; ++g) ssum += red[pp * 256 + g * 32 + cc];
            rowc[pp0 + pp][cc] = ssum;
            a1[((size_t)b * 64 + p0 + pp0 + pp) * 320 + rowch[m] * 32 + cc] = ssum * (1.f/64.f);
        }
        __syncthreads();
    }
    if (colch[m] >= 0){
        #pragma unroll
        for (int kk = 0; kk < 8; ++kk)
            atomicAdd(&a1[((size_t)b * 64 + qb + kk) * 320 + colch[m] * 32 + c],
                      colacc[kk] * (1.f/64.f));
    }
    if (a0i[m] >= 0 && t < 32){
        float tot = 0.f;
        #pragma unroll
        for (int r = 0; r < 16; ++r) tot += rowc[r][t];
        atomicAdd(&a0[(size_t)b * 160 + a0i[m] * 32 + t], tot * (1.f/4096.f));
    }
    if (m == 2){                          // d12 triple-diag -> chunk9 + a0[4]
        #pragma unroll
        for (int r = 0; r < 2; ++r){
            int idx = t + r * 256;        // 0..511
            int pl = idx >> 5, cc = idx & 31;
            int p = p0 + pl;
            float dv = b2f(M[((size_t)p * 64 + p) * 32 + cc]);
            a1[((size_t)b * 64 + p) * 320 + 288 + cc] = dv;
            atomicAdd(&a0[(size_t)b * 160 + 128 + cc], dv * (1.f/64.f));
        }
    }
}

// ---------------------------------------------------------------------------
// K4: u1p/u1t/fov vectors from a1,a0.
__global__ __launch_bounds__(256) void k_uvec(
    const float* __restrict__ a1, const float* __restrict__ a0,
    float* __restrict__ u1p, float* __restrict__ u1t, float* __restrict__ fov,
    const float* __restrict__ W12,  const float* __restrict__ b12,
    const float* __restrict__ W12t, const float* __restrict__ b12t,
    const float* __restrict__ W02,  const float* __restrict__ b02,
    const float* __restrict__ W11,  const float* __restrict__ b11,
    const float* __restrict__ W01,  const float* __restrict__ b01,
    const float* __restrict__ b22)
{
    int b = blockIdx.x >> 3, pg = blockIdx.x & 7;   // 64 blocks
    int t = threadIdx.x;
    int p = pg * 8 + (t >> 5), o = t & 31;
    const float* a1r = a1 + ((size_t)b * 64 + p) * 320;
    const float* a0r = a0 + (size_t)b * 160;
    float accP = b12[o] + b02[o] + b22[o];
    float accT = b12t[o];
    float accF = b11[o] + b01[o];
    for (int f = 0; f < 320; ++f){
        float a = a1r[f];
        accP = fmaf(a, W12 [f * 32 + o], accP);
        accT = fmaf(a, W12t[f * 32 + o], accT);
        accF = fmaf(a, W11 [f * 32 + o], accF);
    }
    for (int g = 0; g < 160; ++g){
        float a = a0r[g];
        accP = fmaf(a, W02[g * 32 + o], accP);
        accF = fmaf(a, W01[g * 32 + o], accF);
    }
    size_t idx = ((size_t)b * 64 + p) * 32 + o;
    u1p[idx] = accP; u1t[idx] = accT; fov[idx] = accF;
}

// ---------------------------------------------------------------------------
// K5 (MFMA): per block (b,p): OUT[q][o] = As[q][f] @ W22[f][o] + epilogue.
__global__ __launch_bounds__(256) void k_out(
    const u16* __restrict__ comps, const float* __restrict__ W22,
    const float* __restrict__ u1p, const float* __restrict__ u1t,
    const float* __restrict__ fov, float* __restrict__ out)
{
    __shared__ __align__(16) u16 As[64 * ASP];   // [q][f], 50.2 KB
    __shared__ __align__(16) u16 Wt[32 * ASP];   // [o][f], 25.1 KB
    int blk = blockIdx.x;                 // b*64+p
    int b = blk >> 6, p = blk & 63;
    int t = threadIdx.x;
    int q = t >> 2, c8 = (t & 3) * 8;

    #pragma unroll
    for (int t6 = 0; t6 < 6; ++t6){
        const u16* cmp = comps + (size_t)t6 * CMPE + (size_t)b * NNC;
        uint4 av = *reinterpret_cast<const uint4*>(cmp + (size_t)p * 2048 + q * 32 + c8);
        uint4 bv = *reinterpret_cast<const uint4*>(cmp + (size_t)q * 2048 + p * 32 + c8);
        *reinterpret_cast<uint4*>(As + q * ASP + t6 * 32 + c8)       = av;
        *reinterpret_cast<uint4*>(As + q * ASP + 192 + t6 * 32 + c8) = bv;
    }
    for (int r = 0; r < 48; ++r){         // W22 [384][32] fp32 -> Wt[o][f] bf16
        int idx = r * 256 + t;
        int f = idx >> 5, o = idx & 31;
        Wt[o * ASP + f] = bf16b(W22[idx]);
    }
    __syncthreads();

    int w = t >> 6, lane = t & 63;
    int l15 = lane & 15, lk = lane >> 4;
    f32x4 acc0 = {0.f, 0.f, 0.f, 0.f};
    f32x4 acc1 = {0.f, 0.f, 0.f, 0.f};
    const u16* arow  = As + (w * 16 + l15) * ASP + lk * 8;
    const u16* b0row = Wt + l15 * ASP + lk * 8;
    const u16* b1row = Wt + (16 + l15) * ASP + lk * 8;
    #pragma unroll
    for (int ks = 0; ks < 12; ++ks){
        bf16x8 af  = *reinterpret_cast<const bf16x8*>(arow  + ks * 32);
        bf16x8 bf0 = *reinterpret_cast<const bf16x8*>(b0row + ks * 32);
        bf16x8 bf1 = *reinterpret_cast<const bf16x8*>(b1row + ks * 32);
        acc0 = __builtin_amdgcn_mfma_f32_16x16x32_bf16(af, bf0, acc0, 0, 0, 0);
        acc1 = __builtin_amdgcn_mfma_f32_16x16x32_bf16(af, bf1, acc1, 0, 0, 0);
    }

    size_t ub = ((size_t)b * 64 + p) * 32;
    float up0 = u1p[ub + l15], up1 = u1p[ub + 16 + l15];
    float fv0 = fov[ub + l15], fv1 = fov[ub + 16 + l15];
    #pragma unroll
    for (int r = 0; r < 4; ++r){
        int qq = w * 16 + lk * 4 + r;
        size_t ob = (((size_t)b * 64 + p) * 64 + qq) * 32;
        size_t tb = ((size_t)b * 64 + qq) * 32;
        float e0 = acc0[r] + up0 + u1t[tb + l15];
        float e1 = acc1[r] + up1 + u1t[tb + 16 + l15];
        if (qq == p){ e0 += fv0; e1 += fv1; }
        out[ob + l15]      = e0;
        out[ob + 16 + l15] = e1;
    }
}

// ---------------------------------------------------------------------------
extern "C" void kernel_launch(void* const* d_in, const int* in_sizes, int n_in,
                              void* d_out, int out_size, void* d_ws, size_t ws_size,
                              hipStream_t stream){
    const float* x    = (const float*)d_in[0];
    const float* W22  = (const float*)d_in[1];
    const float* b22  = (const float*)d_in[2];
    const float* W12  = (const float*)d_in[3];
    const float* b12  = (const float*)d_in[4];
    const float* W12t = (const float*)d_in[5];
    const float* b12t = (const float*)d_in[6];
    const float* W02  = (const float*)d_in[7];
    const float* b02  = (const float*)d_in[8];
    const float* W11  = (const float*)d_in[9];
    const float* b11  = (const float*)d_in[10];
    const float* W01  = (const float*)d_in[11];
    const float* b01  = (const float*)d_in[12];
    float* out = (float*)d_out;
    float* ws  = (float*)d_ws;

    // ws layout (float-slot offsets):
    u16*  p1    = (u16*)ws;                  // u16[8388608]  [0, 4194304)
    u16*  p2    = (u16*)(ws + 4194304);      // u16[8388608]  [4194304, 8388608)
    u16*  comps = (u16*)(ws + 8388608);      // u16[6*CMPE]   [8388608, 11534336)
    u16*  s3ph  = (u16*)(ws + 11534336);     // u16[2097152]  [11534336, 12582912)
    float* a1   = ws + 12582912;             // 163,840 f
    float* a0   = ws + 12746752;             // 1,280 f
    float* u1p  = ws + 12748032;             // 16,384 f (zero-overshoot ok)
    float* u1t  = ws + 12764416;             // 16,384 f
    float* fovv = ws + 12780800;             // 16,384 f

    k_pass1 <<<1024, 256, 0, stream>>>(x, p1, p2, s3ph,
                comps + 3*(size_t)CMPE, comps + 4*(size_t)CMPE, comps + 5*(size_t)CMPE,
                a1);
    k_reduce<<<768, 256, 0, stream>>>(p1, p2, s3ph,
                comps, comps + (size_t)CMPE, comps + 2*(size_t)CMPE);
    k_a1a0  <<<160, 256, 0, stream>>>(comps, a1, a0);
    k_uvec  <<<64,  256, 0, stream>>>(a1, a0, u1p, u1t, fovv,
                W12, b12, W12t, b12t, W02, b02, W11, b11, W01, b01, b22);
    k_out   <<<512, 256, 0, stream>>>(comps, W22, u1p, u1t, fovv, out);
}

// Round 15
// 106.856 us; speedup vs baseline: 1.2374x; 1.2374x over previous
//
#include <hip/hip_runtime.h>
#include <hip/hip_bf16.h>
#include <stdint.h>

// B=8, n=64, C=32, O=32
#define NC   2048      // n*C
#define NNC  131072    // n*n*C
#define N3C  8388608   // n*n*n*C per batch
#define CMPE 1048576   // per-comp elements (B*n*n*C)
#define ASP  392       // k_out LDS row pitch in u16 (16B-aligned: 784B)

typedef unsigned short u16;
typedef short bf16x8 __attribute__((ext_vector_type(8)));
typedef float f32x4  __attribute__((ext_vector_type(4)));

__device__ __forceinline__ u16 bf16b(float x){
    unsigned u = __float_as_uint(x);
    u += 0x7FFFu + ((u >> 16) & 1u);      // RNE
    return (u16)(u >> 16);
}
__device__ __forceinline__ float b2f(u16 h){ return __uint_as_float(((unsigned)h) << 16); }
__device__ __forceinline__ float lo16(unsigned u){ return __uint_as_float(u << 16); }
__device__ __forceinline__ float hi16(unsigned u){ return __uint_as_float(u & 0xFFFF0000u); }
__device__ __forceinline__ void f4acc(float4& a, const float4 b){
    a.x += b.x; a.y += b.y; a.z += b.z; a.w += b.w;
}
__device__ __forceinline__ void addp4(float4& a, const uint2 u){
    a.x += lo16(u.x); a.y += hi16(u.x); a.z += lo16(u.y); a.w += hi16(u.y);
}
__device__ __forceinline__ uint2 pack4(float4 v){
    uint2 r;
    r.x = (unsigned)bf16b(v.x) | ((unsigned)bf16b(v.y) << 16);
    r.y = (unsigned)bf16b(v.z) | ((unsigned)bf16b(v.w) << 16);
    return r;
}
__device__ __forceinline__ uint2 pack4s(float4 v, float s){
    v.x *= s; v.y *= s; v.z *= s; v.w *= s;
    return pack4(v);
}
__device__ __forceinline__ float4 ntload4(const float* p){
    f32x4 r = __builtin_nontemporal_load(reinterpret_cast<const f32x4*>(p));
    return make_float4(r.x, r.y, r.z, r.w);
}

// ---------------------------------------------------------------------------
// K1 (R12 structure + nontemporal x reads): Block=(b, ig, jg, kh). 256
// threads=(ktl,c4). 1024 blocks = 4/CU. Double-buffered s3l [jj][c][ktl]
// (scalar u16 writes, conflict-free b32 reduce reads). One barrier per ii.
// vn-prefetch. First 41 blocks zero the a1/a0 atomic-target region.
__global__ __launch_bounds__(256, 4) void k_pass1(
    const float* __restrict__ x,
    u16* __restrict__ p1, u16* __restrict__ p2,
    u16* __restrict__ s3ph, u16* __restrict__ c_d12,
    u16* __restrict__ c_d13, u16* __restrict__ c_d23,
    float* __restrict__ a1z)
{
    int blk = blockIdx.x;                 // ((b*8+ig)*8+jg)*2+kh
    int kh = blk & 1, jg = (blk >> 1) & 7, ig = (blk >> 4) & 7, b = blk >> 7;
    int t = threadIdx.x;                  // 0..255
    int ktl = t >> 3, kt = kh * 32 + ktl, c4 = (t & 7) * 4;

    if (blk < 41){                        // zero a1+a0 (165120 f; overshoot
        float4 z = make_float4(0,0,0,0);  //  lands in u1p, overwritten later)
        *reinterpret_cast<float4*>(a1z + (size_t)blk * 4096 + 4 * t)        = z;
        *reinterpret_cast<float4*>(a1z + (size_t)blk * 4096 + 1024 + 4 * t) = z;
        *reinterpret_cast<float4*>(a1z + (size_t)blk * 4096 + 2048 + 4 * t) = z;
        *reinterpret_cast<float4*>(a1z + (size_t)blk * 4096 + 3072 + 4 * t) = z;
    }

    __shared__ u16 s3l[2][8][32][34];     // [parity][jj][c][ktl pad34]  ~34KB

    float4 p1a[8];
    #pragma unroll
    for (int a = 0; a < 8; ++a) p1a[a] = make_float4(0,0,0,0);

    const float* xb = x + (size_t)b * N3C + (size_t)ig * 8 * NNC
                        + (size_t)jg * 8 * NC + (size_t)kh * 1024;

    int rjj = t >> 5, rc = t & 31;        // reduce mapping (8 x 32)
    int par = 0;

    float4 v[8];
    #pragma unroll
    for (int jj = 0; jj < 8; ++jj)
        v[jj] = ntload4(xb + (size_t)jj * NC + 4 * t);

    for (int ii = 0; ii < 8; ++ii){
        int i = ig * 8 + ii;
        float4 q = make_float4(0,0,0,0);
        #pragma unroll
        for (int jj = 0; jj < 8; ++jj){
            int j = jg * 8 + jj;
            f4acc(p1a[jj], v[jj]);
            f4acc(q, v[jj]);
            s3l[par][jj][c4 + 0][ktl] = bf16b(v[jj].x);
            s3l[par][jj][c4 + 1][ktl] = bf16b(v[jj].y);
            s3l[par][jj][c4 + 2][ktl] = bf16b(v[jj].z);
            s3l[par][jj][c4 + 3][ktl] = bf16b(v[jj].w);
            if (kt == i)    // d13[b,i,j,c] = x[b,i,j,i,c]
                *reinterpret_cast<uint2*>(c_d13 + (((size_t)(b * 64 + i)) * 64 + j) * 32 + c4) = pack4(v[jj]);
            if (kt == j)    // d23[b,i,j,c] = x[b,i,j,j,c]
                *reinterpret_cast<uint2*>(c_d23 + (((size_t)(b * 64 + i)) * 64 + j) * 32 + c4) = pack4(v[jj]);
            if (i == j)     // d12[b,i,k,c] = x[b,i,i,k,c]; elem = kh*1024+4t
                *reinterpret_cast<uint2*>(c_d12 + ((size_t)(b * 64 + i)) * 2048 + kh * 1024 + 4 * (size_t)t) = pack4(v[jj]);
        }
        // p2 partial row (sum over this jg's 8 j), this k-half
        *reinterpret_cast<uint2*>(p2 + ((size_t)((b * 8 + jg) * 64 + i)) * 2048 + kh * 1024 + 4 * (size_t)t) = pack4(q);

        __syncthreads();                  // publish s3l[par] writes
        // prefetch next ii while the LDS reduce runs
        float4 vn[8];
        if (ii < 7){
            #pragma unroll
            for (int jj = 0; jj < 8; ++jj)
                vn[jj] = ntload4(xb + (size_t)(ii + 1) * NNC + (size_t)jj * NC + 4 * t);
        }
        {   // s3 half-partial reduce over ktl (16 conflict-free b32 reads)
            const unsigned* sp = reinterpret_cast<const unsigned*>(&s3l[par][rjj][rc][0]);
            float s = 0.f;
            #pragma unroll
            for (int g = 0; g < 16; ++g){
                unsigned u = sp[g];
                s += lo16(u) + hi16(u);
            }
            s3ph[(size_t)kh * 1048576 + (((size_t)(b * 64 + i)) * 64 + jg * 8 + rjj) * 32 + rc] = bf16b(s);
        }
        par ^= 1;                         // next ii writes the other buffer
        if (ii < 7){
            #pragma unroll
            for (int jj = 0; jj < 8; ++jj) v[jj] = vn[jj];
        }
    }
    #pragma unroll
    for (int jj = 0; jj < 8; ++jj)
        *reinterpret_cast<uint2*>(p1 + ((size_t)((b * 8 + ig) * 64 + jg * 8 + jj)) * 2048 + kh * 1024 + 4 * (size_t)t) = pack4(p1a[jj]);
}

// ---------------------------------------------------------------------------
// K2: reduce partials -> s1/s2 comps and combine s3 halves (bf16 means).
__global__ __launch_bounds__(256) void k_reduce(
    const u16* __restrict__ p1, const u16* __restrict__ p2,
    const u16* __restrict__ s3ph,
    u16* __restrict__ c_s1, u16* __restrict__ c_s2, u16* __restrict__ c_s3)
{
    int blk = blockIdx.x;
    int b = blk / 96, rr = blk % 96, sx = rr >> 5, ch = rr & 31;
    int t = threadIdx.x;
    if (sx == 2){
        #pragma unroll
        for (int r2 = 0; r2 < 2; ++r2){
            int row = ch * 2 + r2;
            #pragma unroll
            for (int e = 0; e < 2; ++e){
                size_t base = ((size_t)(b * 64 + row)) * 2048 + e * 1024 + 4 * t;
                float4 a = make_float4(0,0,0,0);
                addp4(a, *reinterpret_cast<const uint2*>(s3ph + base));
                addp4(a, *reinterpret_cast<const uint2*>(s3ph + 1048576 + base));
                *reinterpret_cast<uint2*>(c_s3 + base) = pack4s(a, 1.f/64.f);
            }
        }
        return;
    }
    const u16* P = sx ? p2 : p1;
    u16* O = sx ? c_s2 : c_s1;
    #pragma unroll
    for (int r2 = 0; r2 < 2; ++r2){
        int row = ch * 2 + r2;
        float4 a0v = make_float4(0,0,0,0), a1v = make_float4(0,0,0,0);
        #pragma unroll
        for (int g = 0; g < 8; ++g){
            const u16* src = P + ((size_t)((b * 8 + g) * 64 + row)) * 2048;
            addp4(a0v, *reinterpret_cast<const uint2*>(src + 4 * t));
            addp4(a1v, *reinterpret_cast<const uint2*>(src + 1024 + 4 * t));
        }
        u16* ob = O + ((size_t)(b * 64 + row)) * 2048;
        *reinterpret_cast<uint2*>(ob + 4 * t)        = pack4s(a0v, 1.f/64.f);
        *reinterpret_cast<uint2*>(ob + 1024 + 4 * t) = pack4s(a1v, 1.f/64.f);
    }
}

// ---------------------------------------------------------------------------
// K3: a1 [B][64][320], a0 [B][160] from bf16 comps. 160 blocks:
// (b*5+m)*4 + pc. Row-chunks direct-write; col/a0/diag via atomicAdd
// (region pre-zeroed by k_pass1).
__global__ __launch_bounds__(256) void k_a1a0(
    const u16* __restrict__ comps,
    float* __restrict__ a1, float* __restrict__ a0)
{
    int blk = blockIdx.x;                 // 160: (b*5+m)*4 + pc
    int pc = blk & 3, m = (blk >> 2) % 5, b = blk / 20;
    const int cidx [5] = {0, 1, 3, 4, 5};
    const int rowch[5] = {1, 2, 4, 6, 8};
    const int colch[5] = {0, -1, 3, 5, 7};
    const int a0i  [5] = {0, -1, 1, 2, 3};

    const u16* M = comps + (size_t)cidx[m] * CMPE + (size_t)b * NNC;
    int t = threadIdx.x, c = t & 31, qb = (t >> 5) * 8;
    int p0 = pc * 16;
    float colacc[8] = {0,0,0,0,0,0,0,0};
    __shared__ float red[2048];
    __shared__ float rowc[16][32];
    for (int pp0 = 0; pp0 < 16; pp0 += 8){
        #pragma unroll
        for (int pp = 0; pp < 8; ++pp){
            const u16* row = M + (size_t)(p0 + pp0 + pp) * 2048;
            float part = 0.f;
            #pragma unroll
            for (int kk = 0; kk < 8; ++kk){
                float v = b2f(row[(qb + kk) * 32 + c]);
                colacc[kk] += v; part += v;
            }
            red[pp * 256 + t] = part;
        }
        __syncthreads();
        {
            int pp = t >> 5, cc = t & 31;
            float ssum = 0.f;
            #pragma unroll
            for (int g = 0; g < 8; ++g) ssum += red[pp * 256 + g * 32 + cc];
            rowc[pp0 + pp][cc] = ssum;
            a1[((size_t)b * 64 + p0 + pp0 + pp) * 320 + rowch[m] * 32 + cc] = ssum * (1.f/64.f);
        }
        __syncthreads();
    }
    if (colch[m] >= 0){
        #pragma unroll
        for (int kk = 0; kk < 8; ++kk)
            atomicAdd(&a1[((size_t)b * 64 + qb + kk) * 320 + colch[m] * 32 + c],
                      colacc[kk] * (1.f/64.f));
    }
    if (a0i[m] >= 0 && t < 32){
        float tot = 0.f;
        #pragma unroll
        for (int r = 0; r < 16; ++r) tot += rowc[r][t];
        atomicAdd(&a0[(size_t)b * 160 + a0i[m] * 32 + t], tot * (1.f/4096.f));
    }
    if (m == 2){                          // d12 triple-diag -> chunk9 + a0[4]
        #pragma unroll
        for (int r = 0; r < 2; ++r){
            int idx = t + r * 256;        // 0..511
            int pl = idx >> 5, cc = idx & 31;
            int p = p0 + pl;
            float dv = b2f(M[((size_t)p * 64 + p) * 32 + cc]);
            a1[((size_t)b * 64 + p) * 320 + 288 + cc] = dv;
            atomicAdd(&a0[(size_t)b * 160 + 128 + cc], dv * (1.f/64.f));
        }
    }
}

// ---------------------------------------------------------------------------
// K4: u1p/u1t/fov vectors from a1,a0.
__global__ __launch_bounds__(256) void k_uvec(
    const float* __restrict__ a1, const float* __restrict__ a0,
    float* __restrict__ u1p, float* __restrict__ u1t, float* __restrict__ fov,
    const float* __restrict__ W12,  const float* __restrict__ b12,
    const float* __restrict__ W12t, const float* __restrict__ b12t,
    const float* __restrict__ W02,  const float* __restrict__ b02,
    const float* __restrict__ W11,  const float* __restrict__ b11,
    const float* __restrict__ W01,  const float* __restrict__ b01,
    const float* __restrict__ b22)
{
    int b = blockIdx.x >> 3, pg = blockIdx.x & 7;   // 64 blocks
    int t = threadIdx.x;
    int p = pg * 8 + (t >> 5), o = t & 31;
    const float* a1r = a1 + ((size_t)b * 64 + p) * 320;
    const float* a0r = a0 + (size_t)b * 160;
    float accP = b12[o] + b02[o] + b22[o];
    float accT = b12t[o];
    float accF = b11[o] + b01[o];
    for (int f = 0; f < 320; ++f){
        float a = a1r[f];
        accP = fmaf(a, W12 [f * 32 + o], accP);
        accT = fmaf(a, W12t[f * 32 + o], accT);
        accF = fmaf(a, W11 [f * 32 + o], accF);
    }
    for (int g = 0; g < 160; ++g){
        float a = a0r[g];
        accP = fmaf(a, W02[g * 32 + o], accP);
        accF = fmaf(a, W01[g * 32 + o], accF);
    }
    size_t idx = ((size_t)b * 64 + p) * 32 + o;
    u1p[idx] = accP; u1t[idx] = accT; fov[idx] = accF;
}

// ---------------------------------------------------------------------------
// K5 (MFMA): per block (b,p): OUT[q][o] = As[q][f] @ W22[f][o] + epilogue.
__global__ __launch_bounds__(256) void k_out(
    const u16* __restrict__ comps, const float* __restrict__ W22,
    const float* __restrict__ u1p, const float* __restrict__ u1t,
    const float* __restrict__ fov, float* __restrict__ out)
{
    __shared__ __align__(16) u16 As[64 * ASP];   // [q][f], 50.2 KB
    __shared__ __align__(16) u16 Wt[32 * ASP];   // [o][f], 25.1 KB
    int blk = blockIdx.x;                 // b*64+p
    int b = blk >> 6, p = blk & 63;
    int t = threadIdx.x;
    int q = t >> 2, c8 = (t & 3) * 8;

    #pragma unroll
    for (int t6 = 0; t6 < 6; ++t6){
        const u16* cmp = comps + (size_t)t6 * CMPE + (size_t)b * NNC;
        uint4 av = *reinterpret_cast<const uint4*>(cmp + (size_t)p * 2048 + q * 32 + c8);
        uint4 bv = *reinterpret_cast<const uint4*>(cmp + (size_t)q * 2048 + p * 32 + c8);
        *reinterpret_cast<uint4*>(As + q * ASP + t6 * 32 + c8)       = av;
        *reinterpret_cast<uint4*>(As + q * ASP + 192 + t6 * 32 + c8) = bv;
    }
    for (int r = 0; r < 48; ++r){         // W22 [384][32] fp32 -> Wt[o][f] bf16
        int idx = r * 256 + t;
        int f = idx >> 5, o = idx & 31;
        Wt[o * ASP + f] = bf16b(W22[idx]);
    }
    __syncthreads();

    int w = t >> 6, lane = t & 63;
    int l15 = lane & 15, lk = lane >> 4;
    f32x4 acc0 = {0.f, 0.f, 0.f, 0.f};
    f32x4 acc1 = {0.f, 0.f, 0.f, 0.f};
    const u16* arow  = As + (w * 16 + l15) * ASP + lk * 8;
    const u16* b0row = Wt + l15 * ASP + lk * 8;
    const u16* b1row = Wt + (16 + l15) * ASP + lk * 8;
    #pragma unroll
    for (int ks = 0; ks < 12; ++ks){
        bf16x8 af  = *reinterpret_cast<const bf16x8*>(arow  + ks * 32);
        bf16x8 bf0 = *reinterpret_cast<const bf16x8*>(b0row + ks * 32);
        bf16x8 bf1 = *reinterpret_cast<const bf16x8*>(b1row + ks * 32);
        acc0 = __builtin_amdgcn_mfma_f32_16x16x32_bf16(af, bf0, acc0, 0, 0, 0);
        acc1 = __builtin_amdgcn_mfma_f32_16x16x32_bf16(af, bf1, acc1, 0, 0, 0);
    }

    size_t ub = ((size_t)b * 64 + p) * 32;
    float up0 = u1p[ub + l15], up1 = u1p[ub + 16 + l15];
    float fv0 = fov[ub + l15], fv1 = fov[ub + 16 + l15];
    #pragma unroll
    for (int r = 0; r < 4; ++r){
        int qq = w * 16 + lk * 4 + r;
        size_t ob = (((size_t)b * 64 + p) * 64 + qq) * 32;
        size_t tb = ((size_t)b * 64 + qq) * 32;
        float e0 = acc0[r] + up0 + u1t[tb + l15];
        float e1 = acc1[r] + up1 + u1t[tb + 16 + l15];
        if (qq == p){ e0 += fv0; e1 += fv1; }
        out[ob + l15]      = e0;
        out[ob + 16 + l15] = e1;
    }
}

// ---------------------------------------------------------------------------
extern "C" void kernel_launch(void* const* d_in, const int* in_sizes, int n_in,
                              void* d_out, int out_size, void* d_ws, size_t ws_size,
                              hipStream_t stream){
    const float* x    = (const float*)d_in[0];
    const float* W22  = (const float*)d_in[1];
    const float* b22  = (const float*)d_in[2];
    const float* W12  = (const float*)d_in[3];
    const float* b12  = (const float*)d_in[4];
    const float* W12t = (const float*)d_in[5];
    const float* b12t = (const float*)d_in[6];
    const float* W02  = (const float*)d_in[7];
    const float* b02  = (const float*)d_in[8];
    const float* W11  = (const float*)d_in[9];
    const float* b11  = (const float*)d_in[10];
    const float* W01  = (const float*)d_in[11];
    const float* b01  = (const float*)d_in[12];
    float* out = (float*)d_out;
    float* ws  = (float*)d_ws;

    // ws layout (float-slot offsets):
    u16*  p1    = (u16*)ws;                  // u16[8388608]  [0, 4194304)
    u16*  p2    = (u16*)(ws + 4194304);      // u16[8388608]  [4194304, 8388608)
    u16*  comps = (u16*)(ws + 8388608);      // u16[6*CMPE]   [8388608, 11534336)
    u16*  s3ph  = (u16*)(ws + 11534336);     // u16[2097152]  [11534336, 12582912)
    float* a1   = ws + 12582912;             // 163,840 f
    float* a0   = ws + 12746752;             // 1,280 f
    float* u1p  = ws + 12748032;             // 16,384 f (zero-overshoot ok)
    float* u1t  = ws + 12764416;             // 16,384 f
    float* fovv = ws + 12780800;             // 16,384 f

    k_pass1 <<<1024, 256, 0, stream>>>(x, p1, p2, s3ph,
                comps + 3*(size_t)CMPE, comps + 4*(size_t)CMPE, comps + 5*(size_t)CMPE,
                a1);
    k_reduce<<<768, 256, 0, stream>>>(p1, p2, s3ph,
                comps, comps + (size_t)CMPE, comps + 2*(size_t)CMPE);
    k_a1a0  <<<160, 256, 0, stream>>>(comps, a1, a0);
    k_uvec  <<<64,  256, 0, stream>>>(a1, a0, u1p, u1t, fovv,
                W12, b12, W12t, b12t, W02, b02, W11, b11, W01, b01, b22);
    k_out   <<<512, 256, 0, stream>>>(comps, W22, u1p, u1t, fovv, out);
}